// Round 5
// baseline (94.603 us; speedup 1.0000x reference)
//
#include <hip/hip_runtime.h>
#include <stdint.h>

typedef unsigned short u16;
typedef unsigned int u32;
typedef unsigned long long u64;

typedef __bf16 bf16x8 __attribute__((ext_vector_type(8)));
typedef float f32x4 __attribute__((ext_vector_type(4)));
typedef u16 u16x8 __attribute__((ext_vector_type(8)));

#define NQ 512
#define NC 16
#define NH 128
#define NB 2048
#define ESTRIDE 136    // sE row stride in u16
#define HSTRIDE 24     // sHB row stride in u16
#define QE_KEYS (513*128)   // 65664 u16 keys
#define WT_OFF  QE_KEYS     // u16 offset of bf16 W copy in d_ws
#define GW_ELEMS (128*128)

static __device__ __forceinline__ u16 f2bf_rne(float f){
  u32 u = __float_as_uint(f);
  u += 0x7fffu + ((u>>16)&1u);
  return (u16)(u>>16);
}
static __device__ __forceinline__ u32 pack_rne(float lo, float hi){
  return (u32)f2bf_rne(lo) | ((u32)f2bf_rne(hi)<<16);
}
// monotone key: unsigned compare on keys == float compare on bf16 values
static __device__ __forceinline__ u16 key_of(float f){
  u16 b = f2bf_rne(f);
  return (b & 0x8000u) ? (u16)~b : (u16)(b | 0x8000u);
}
static __device__ __forceinline__ u16 unkey(u16 k){
  return (k & 0x8000u) ? (u16)(k ^ 0x8000u) : (u16)~k;
}

union Frag { u32 u[4]; uint4 u4; bf16x8 f; };
union U8   { u16x8 v; int w[4]; uint4 u4; u16 h[8]; };

// ---- prepass: qe fp32 -> u16 keys (row 512 forced to key(0)=0x8000); gw fp32 -> bf16 ----
__global__ void prepass_kernel(const float* __restrict__ qe,
                               const float* __restrict__ gw,
                               u16* __restrict__ ws)
{
  int idx = blockIdx.x * 256 + threadIdx.x;
  if (idx < QE_KEYS/8) {                       // 8208 threads: key table
    int i8 = idx * 8;
    uint4 o;
    if (i8 >= 512*NH) {                        // row 512: key of +0.0
      o.x = 0x80008000u; o.y = 0x80008000u; o.z = 0x80008000u; o.w = 0x80008000u;
    } else {
      const float4* p = (const float4*)(qe + i8);
      float4 a = p[0], b = p[1];
      o.x = (u32)key_of(a.x) | ((u32)key_of(a.y)<<16);
      o.y = (u32)key_of(a.z) | ((u32)key_of(a.w)<<16);
      o.z = (u32)key_of(b.x) | ((u32)key_of(b.y)<<16);
      o.w = (u32)key_of(b.z) | ((u32)key_of(b.w)<<16);
    }
    *(uint4*)(ws + i8) = o;
  } else if (idx < QE_KEYS/8 + GW_ELEMS/8) {   // 2048 threads: W -> bf16
    int j8 = (idx - QE_KEYS/8) * 8;
    const float4* p = (const float4*)(gw + j8);
    float4 a = p[0], b = p[1];
    uint4 o;
    o.x = pack_rne(a.x, a.y); o.y = pack_rne(a.z, a.w);
    o.z = pack_rne(b.x, b.y); o.w = pack_rne(b.z, b.w);
    *(uint4*)(ws + WT_OFF + j8) = o;
  }
}

__global__ __launch_bounds__(256, 6)
void core_snapshot_kernel(const int* __restrict__ la,
                          const float* __restrict__ adj,
                          const u16* __restrict__ ws,   // keys + bf16 W
                          const float* __restrict__ gb,
                          float* __restrict__ outp)
{
  __shared__ __align__(16) u16 sE[16*ESTRIDE];    // core_embs (bf16)
  __shared__ __align__(16) u16 sHB[128*HSTRIDE];  // H transposed: [o][core]
  __shared__ u16 sList[16*64];
  __shared__ u32 sHist[8*16];
  __shared__ u32 sBase[8*16];
  __shared__ u32 sCnt[16];
  __shared__ float sDinv[16];

  const int tid  = threadIdx.x;
  const int lane = tid & 63;
  const int wv   = tid >> 6;
  const int m    = lane & 15;
  const int quad = lane >> 4;
  const int b    = blockIdx.x;
  const u16* qt  = ws;              // key table
  const u16* wt  = ws + WT_OFF;     // bf16 W, row-major [o][h]

  // ---- phase 1: assignments + per-chunk histograms via ballots ----
  int av[2]; u32 intra[2];
  const u64 lmask = (1ull << lane) - 1ull;
  #pragma unroll
  for (int r = 0; r < 2; ++r) {
    int ch = wv*2 + r;
    av[r] = la[b*NQ + ch*64 + lane];
  }
  #pragma unroll
  for (int r = 0; r < 2; ++r) {
    int ch = wv*2 + r;
    #pragma unroll
    for (int c = 0; c < 16; ++c) {
      u64 mk = __ballot(av[r] == c);
      if (lane == c)  sHist[ch*16 + c] = (u32)__popcll(mk);
      if (av[r] == c) intra[r] = (u32)__popcll(mk & lmask);
    }
  }
  if (tid < 16) {   // dinv from adjacency column sums
    float s = 0.f;
    for (int i = 0; i < 16; ++i) s += adj[i*16 + tid];
    sDinv[tid] = (s > 0.f) ? (1.0f / sqrtf(s)) : 0.f;
  }
  __syncthreads();
  if (tid < 16) {   // exclusive prefix over chunks
    u32 run = 0;
    #pragma unroll
    for (int ch = 0; ch < 8; ++ch) { sBase[ch*16 + tid] = run; run += sHist[ch*16 + tid]; }
    sCnt[tid] = run;
  }
  __syncthreads();
  #pragma unroll
  for (int r = 0; r < 2; ++r) {
    int ch = wv*2 + r;
    u32 rank = sBase[ch*16 + av[r]] + intra[r];
    if (rank < 64) sList[av[r]*64 + rank] = (u16)(ch*64 + lane);  // first-64 drop
  }
  __syncthreads();

  // ---- phase 2: interleaved key gather (4 cores in flight) + packed-u16 max ----
  {
    const int c0 = wv*4;
    int cnt4[4], itr[4];
    #pragma unroll
    for (int cc = 0; cc < 4; ++cc) {
      cnt4[cc] = (int)min(sCnt[c0+cc], 64u);
      itr[cc]  = (cnt4[cc] + 3) >> 2;
    }
    int kmax = max(max(itr[0], itr[1]), max(itr[2], itr[3]));
    U8 A[4];
    #pragma unroll
    for (int cc = 0; cc < 4; ++cc) A[cc].v = (u16x8)0;   // key 0 < all value keys
    const u16* qbase = qt + m*8;
    for (int k = 0; k < kmax; ++k) {
      int slot = k*4 + quad;
      int qv[4];
      #pragma unroll
      for (int cc = 0; cc < 4; ++cc)
        qv[cc] = (slot < cnt4[cc]) ? (int)sList[(c0+cc)*64 + slot] : 512;  // row 512 = key(+0)
      U8 T[4];
      #pragma unroll
      for (int cc = 0; cc < 4; ++cc)
        T[cc].u4 = *(const uint4*)(qbase + qv[cc]*NH);
      #pragma unroll
      for (int cc = 0; cc < 4; ++cc)
        A[cc].v = __builtin_elementwise_max(A[cc].v, T[cc].v);
    }
    #pragma unroll
    for (int cc = 0; cc < 4; ++cc) {
      U8 Bv;
      #pragma unroll
      for (int j = 0; j < 4; ++j) Bv.w[j] = __shfl_xor(A[cc].w[j], 16);
      A[cc].v = __builtin_elementwise_max(A[cc].v, Bv.v);
      #pragma unroll
      for (int j = 0; j < 4; ++j) Bv.w[j] = __shfl_xor(A[cc].w[j], 32);
      A[cc].v = __builtin_elementwise_max(A[cc].v, Bv.v);
      if (cnt4[cc] < 64) {           // padding slots contribute +0 (relu)
        U8 Z; Z.v = (u16x8)(u16)0x8000u;
        A[cc].v = __builtin_elementwise_max(A[cc].v, Z.v);
      }
      if (quad == 0) {               // untransform keys -> bf16, store row c
        uint4 e;
        e.x = (u32)unkey(A[cc].h[0]) | ((u32)unkey(A[cc].h[1])<<16);
        e.y = (u32)unkey(A[cc].h[2]) | ((u32)unkey(A[cc].h[3])<<16);
        e.z = (u32)unkey(A[cc].h[4]) | ((u32)unkey(A[cc].h[5])<<16);
        e.w = (u32)unkey(A[cc].h[6]) | ((u32)unkey(A[cc].h[7])<<16);
        *(uint4*)&sE[(c0+cc)*ESTRIDE + m*8] = e;
      }
    }
  }
  __syncthreads();

  // ---- phase 3: H = E @ W^T via MFMA -> sHB[o][core] (bf16) ----
  {
    bf16x8 af[4];
    #pragma unroll
    for (int ks = 0; ks < 4; ++ks)
      af[ks] = *(const bf16x8*)&sE[m*ESTRIDE + ks*32 + quad*8];
    #pragma unroll
    for (int t = 0; t < 2; ++t) {
      int o = (wv*2 + t)*16 + m;
      f32x4 acc = {0.f, 0.f, 0.f, 0.f};
      #pragma unroll
      for (int ks = 0; ks < 4; ++ks) {
        bf16x8 bfr = *(const bf16x8*)(wt + o*NH + ks*32 + quad*8);
        acc = __builtin_amdgcn_mfma_f32_16x16x32_bf16(af[ks], bfr, acc, 0, 0, 0);
      }
      // C/D layout: col=lane&15 (o in tile), row=quad*4+reg (core)
      *(u32*)&sHB[o*HSTRIDE + quad*4]     = pack_rne(acc[0], acc[1]);
      *(u32*)&sHB[o*HSTRIDE + quad*4 + 2] = pack_rne(acc[2], acc[3]);
    }
  }
  __syncthreads();

  // ---- phase 4: out = A_norm @ H + bias (K padded 16->32) ----
  Frag afr2;
  #pragma unroll
  for (int jj = 0; jj < 4; ++jj) {
    float lo = 0.f, hi = 0.f;
    if (quad < 2) {
      int k0 = quad*8 + jj*2;
      lo = adj[m*16 + k0]     * sDinv[m] * sDinv[k0];
      hi = adj[m*16 + k0 + 1] * sDinv[m] * sDinv[k0 + 1];
    }
    afr2.u[jj] = pack_rne(lo, hi);
  }
  #pragma unroll
  for (int t = 0; t < 2; ++t) {
    int o = (wv*2 + t)*16 + m;
    float biasv = gb[(wv*2 + t)*16 + m];
    Frag bfr;
    if (quad < 2) bfr.u4 = *(const uint4*)&sHB[o*HSTRIDE + quad*8];
    else { bfr.u[0]=0; bfr.u[1]=0; bfr.u[2]=0; bfr.u[3]=0; }
    f32x4 acc = {biasv, biasv, biasv, biasv};
    acc = __builtin_amdgcn_mfma_f32_16x16x32_bf16(afr2.f, bfr.f, acc, 0, 0, 0);
    float* op = outp + b*(NC*NH) + o;
    #pragma unroll
    for (int r = 0; r < 4; ++r) op[(quad*4 + r)*NH] = acc[r];
  }
}

extern "C" void kernel_launch(void* const* d_in, const int* in_sizes, int n_in,
                              void* d_out, int out_size, void* d_ws, size_t ws_size,
                              hipStream_t stream) {
  const int*   la  = (const int*)d_in[0];    // (2048, 512) int32
  const float* adj = (const float*)d_in[1];  // (16,16) fp32
  const float* qe  = (const float*)d_in[2];  // (513,128) fp32
  const float* gw  = (const float*)d_in[3];  // (128,128) fp32
  const float* gb  = (const float*)d_in[4];  // (128,) fp32
  float* outp = (float*)d_out;               // (2048,16,128) fp32
  u16* ws = (u16*)d_ws;                      // keys (131328 B) + bf16 W (32768 B)

  int pre_threads = QE_KEYS/8 + GW_ELEMS/8;  // 10256
  prepass_kernel<<<(pre_threads + 255)/256, 256, 0, stream>>>(qe, gw, ws);
  core_snapshot_kernel<<<NB, 256, 0, stream>>>(la, adj, ws, gb, outp);
}